// Round 3
// baseline (729.675 us; speedup 1.0000x reference)
//
#include <hip/hip_runtime.h>
#include <hip/hip_bf16.h>
#include <math.h>

#define N_NODES 100000
#define N_EDGES 1600000
#define IN_CH 128
#define OUT_CH 128
#define EDGE_DIM 6
#define STATE_DIM 5
#define XS_DIM (IN_CH + STATE_DIM)   // 133
#define XS_STRIDE 136                // padded row stride in LDS
#define NODES_PER_BLOCK 32

// ---------------------------------------------------------------------------
// Kernel 1: per-node GEMMs. 32 nodes/block to amortize weight loads.
//   Y[n][c]   = xs[n] @ W_neg[0:133] + b_neg      -> ws (bf16, b_neg folded)
//   out[n][c] = elu( xs[n] @ W_root + b_root )    -> d_out (fp32)
// ---------------------------------------------------------------------------
__global__ __launch_bounds__(256) void node_gemm(
    const float* __restrict__ x, const float* __restrict__ gs,
    const float* __restrict__ Wneg, const float* __restrict__ bneg,
    const float* __restrict__ Wroot, const float* __restrict__ broot,
    __hip_bfloat16* __restrict__ Yb, float* __restrict__ out)
{
    __shared__ float xs_s[NODES_PER_BLOCK * XS_STRIDE];
    const int tid = threadIdx.x;
    const int n0  = blockIdx.x * NODES_PER_BLOCK;
    const int col  = tid & 127;
    const int half = tid >> 7;   // 0 or 1

    // stage x: 256 threads cover 2 rows per iteration, 16 iterations = 32 rows
#pragma unroll
    for (int i = 0; i < 16; ++i) {
        int t = 2 * i + half;
        xs_s[t * XS_STRIDE + col] = x[(long)(n0 + t) * IN_CH + col];
    }
    if (tid < NODES_PER_BLOCK * STATE_DIM) {
        int t = tid / STATE_DIM, j = tid % STATE_DIM;
        xs_s[t * XS_STRIDE + IN_CH + j] = gs[(long)(n0 + t) * STATE_DIM + j];
    }
    __syncthreads();

    float accN[16], accR[16];
#pragma unroll
    for (int t = 0; t < 16; ++t) { accN[t] = 0.f; accR[t] = 0.f; }

    const int rowbase = half * 16;
    for (int k = 0; k < 132; k += 4) {
        float wn0 = Wneg[(k + 0) * 128 + col];
        float wn1 = Wneg[(k + 1) * 128 + col];
        float wn2 = Wneg[(k + 2) * 128 + col];
        float wn3 = Wneg[(k + 3) * 128 + col];
        float wr0 = Wroot[(k + 0) * 128 + col];
        float wr1 = Wroot[(k + 1) * 128 + col];
        float wr2 = Wroot[(k + 2) * 128 + col];
        float wr3 = Wroot[(k + 3) * 128 + col];
#pragma unroll
        for (int t = 0; t < 16; ++t) {
            const float4 v = *(const float4*)&xs_s[(rowbase + t) * XS_STRIDE + k];
            accN[t] = fmaf(v.x, wn0, accN[t]);
            accN[t] = fmaf(v.y, wn1, accN[t]);
            accN[t] = fmaf(v.z, wn2, accN[t]);
            accN[t] = fmaf(v.w, wn3, accN[t]);
            accR[t] = fmaf(v.x, wr0, accR[t]);
            accR[t] = fmaf(v.y, wr1, accR[t]);
            accR[t] = fmaf(v.z, wr2, accR[t]);
            accR[t] = fmaf(v.w, wr3, accR[t]);
        }
    }
    {   // k = 132 remainder
        float wn = Wneg[132 * 128 + col];
        float wr = Wroot[132 * 128 + col];
#pragma unroll
        for (int t = 0; t < 16; ++t) {
            float v = xs_s[(rowbase + t) * XS_STRIDE + 132];
            accN[t] = fmaf(v, wn, accN[t]);
            accR[t] = fmaf(v, wr, accR[t]);
        }
    }

    const float bn = bneg[col];
    const float br = broot[col];
#pragma unroll
    for (int t = 0; t < 16; ++t) {
        int n = n0 + rowbase + t;
        Yb[(long)n * 128 + col] = __float2bfloat16(accN[t] + bn);
        float r = accR[t] + br;
        out[(long)n * 128 + col] = (r > 0.f) ? r : (expf(r) - 1.f);
    }
}

// ---------------------------------------------------------------------------
// CSR build: memset counts (host-side memsetAsync) -> histogram -> scan -> scatter
// ---------------------------------------------------------------------------
__global__ __launch_bounds__(256) void histogram(const int* __restrict__ idx,
                                                 int* __restrict__ cnt) {
    int e = blockIdx.x * 256 + threadIdx.x;
    if (e < N_EDGES) atomicAdd(&cnt[idx[e]], 1);   // idx row 0 = dst/segment
}

// Single-block scan: 1024 threads x 16 items = 16384/chunk -> 7 chunks.
__global__ __launch_bounds__(1024) void scan_counts(const int* __restrict__ cnt,
                                                    int* __restrict__ off,
                                                    int* __restrict__ cursor) {
    __shared__ int wsum[16];
    const int tid  = threadIdx.x;
    const int lane = tid & 63;
    const int wid  = tid >> 6;
    int carry = 0;
    for (int c0 = 0; c0 < N_NODES; c0 += 16384) {
        int i0 = c0 + tid * 16;
        int v[16], s = 0;
#pragma unroll
        for (int j = 0; j < 16; ++j) {
            v[j] = (i0 + j < N_NODES) ? cnt[i0 + j] : 0;
            s += v[j];
        }
        int x = s;   // inclusive wave scan of per-thread sums
#pragma unroll
        for (int d = 1; d < 64; d <<= 1) {
            int t = __shfl_up(x, d);
            if (lane >= d) x += t;
        }
        if (lane == 63) wsum[wid] = x;
        __syncthreads();
        if (wid == 0 && lane < 16) {
            int w = wsum[lane];
#pragma unroll
            for (int d = 1; d < 16; d <<= 1) {
                int t = __shfl_up(w, d);
                if (lane >= d) w += t;
            }
            wsum[lane] = w;   // inclusive across waves
        }
        __syncthreads();
        int wprefix = (wid > 0) ? wsum[wid - 1] : 0;
        int total   = wsum[15];
        int excl = carry + wprefix + (x - s);
#pragma unroll
        for (int j = 0; j < 16; ++j) {
            if (i0 + j < N_NODES) { off[i0 + j] = excl; cursor[i0 + j] = excl; }
            excl += v[j];
        }
        carry += total;
        __syncthreads();   // protect wsum before next chunk
    }
}

__global__ __launch_bounds__(256) void scatter_edges(const int* __restrict__ idx,
                                                     int* __restrict__ cursor,
                                                     int* __restrict__ eids) {
    int e = blockIdx.x * 256 + threadIdx.x;
    if (e < N_EDGES) {
        int pos = atomicAdd(&cursor[idx[e]], 1);
        eids[pos] = e;
    }
}

// ---------------------------------------------------------------------------
// Aggregate: one wave per dst node. Y is bf16 (exact expand via bits<<16).
// ---------------------------------------------------------------------------
__global__ __launch_bounds__(256) void aggregate(
    const int* __restrict__ idx,     // row1 (src) at idx + N_EDGES
    const float* __restrict__ ea,
    const float* __restrict__ Wneg,  // bottom 6 rows at 133*128
    const __hip_bfloat16* __restrict__ Yb,
    const int* __restrict__ off, const int* __restrict__ cnt,
    const int* __restrict__ eids,
    float* __restrict__ out)
{
    const int lane = threadIdx.x & 63;
    const int n    = blockIdx.x * 4 + (threadIdx.x >> 6);
    if (n >= N_NODES) return;

    const float2* wb2 = (const float2*)(Wneg + 133 * 128);
    float2 wb[EDGE_DIM];
#pragma unroll
    for (int j = 0; j < EDGE_DIM; ++j) wb[j] = wb2[j * 64 + lane];

    const int start = off[n];
    const int deg   = cnt[n];
    float accx = 0.f, accy = 0.f;

    for (int base = 0; base < deg; base += 64) {
        const int m = min(64, deg - base);
        int src = 0;
        float ea6[EDGE_DIM];
#pragma unroll
        for (int j = 0; j < EDGE_DIM; ++j) ea6[j] = 0.f;
        if (lane < m) {
            int eid = eids[start + base + lane];
            src = idx[N_EDGES + eid];
            const float* er = ea + (long)eid * EDGE_DIM;
#pragma unroll
            for (int j = 0; j < EDGE_DIM; ++j) ea6[j] = er[j];
        }
#pragma unroll 4
        for (int e = 0; e < m; ++e) {
            int s = __shfl(src, e);
            ushort2 u = ((const ushort2*)(Yb + (long)s * 128))[lane];
            float tx = __uint_as_float((unsigned)u.x << 16);
            float ty = __uint_as_float((unsigned)u.y << 16);
#pragma unroll
            for (int j = 0; j < EDGE_DIM; ++j) {
                float a = __shfl(ea6[j], e);
                tx = fmaf(a, wb[j].x, tx);
                ty = fmaf(a, wb[j].y, ty);
            }
            tx = (tx > 0.f) ? tx : (expf(tx) - 1.f);
            ty = (ty > 0.f) ? ty : (expf(ty) - 1.f);
            accx += tx;
            accy += ty;
        }
    }

    float2* orow = (float2*)(out + (long)n * 128);
    float2 o = orow[lane];          // root term from node_gemm
    o.x += accx;
    o.y += accy;
    orow[lane] = o;
}

extern "C" void kernel_launch(void* const* d_in, const int* in_sizes, int n_in,
                              void* d_out, int out_size, void* d_ws, size_t ws_size,
                              hipStream_t stream) {
    const float* x     = (const float*)d_in[0];
    const int*   idx   = (const int*)  d_in[1];
    const float* ea    = (const float*)d_in[2];
    const float* gs    = (const float*)d_in[3];
    const float* Wneg  = (const float*)d_in[4];
    const float* bneg  = (const float*)d_in[5];
    const float* Wroot = (const float*)d_in[6];
    const float* broot = (const float*)d_in[7];
    float* out = (float*)d_out;

    // ws layout:
    //   Yb     : N*128 bf16  (25.6 MB)
    //   cnt    : N int
    //   off    : N int
    //   cursor : N int
    //   eids   : E int       (6.4 MB)
    char* w = (char*)d_ws;
    __hip_bfloat16* Yb = (__hip_bfloat16*)w;      w += (size_t)N_NODES * 128 * 2;
    int*   cnt   = (int*)w;                       w += (size_t)N_NODES * 4;
    int*   off   = (int*)w;                       w += (size_t)N_NODES * 4;
    int*   cur   = (int*)w;                       w += (size_t)N_NODES * 4;
    int*   eids  = (int*)w;

    const int nb_edges = (N_EDGES + 255) / 256;

    node_gemm<<<N_NODES / NODES_PER_BLOCK, 256, 0, stream>>>(
        x, gs, Wneg, bneg, Wroot, broot, Yb, out);
    hipMemsetAsync(cnt, 0, (size_t)N_NODES * 4, stream);
    histogram<<<nb_edges, 256, 0, stream>>>(idx, cnt);
    scan_counts<<<1, 1024, 0, stream>>>(cnt, off, cur);
    scatter_edges<<<nb_edges, 256, 0, stream>>>(idx, cur, eids);
    aggregate<<<(N_NODES + 3) / 4, 256, 0, stream>>>(idx, ea, Wneg, Yb, off, cnt, eids, out);
}

// Round 4
// 663.865 us; speedup vs baseline: 1.0991x; 1.0991x over previous
//
#include <hip/hip_runtime.h>
#include <hip/hip_bf16.h>
#include <math.h>

#define N_NODES 100000
#define N_EDGES 1600000
#define IN_CH 128
#define OUT_CH 128
#define EDGE_DIM 6
#define STATE_DIM 5
#define XS_DIM 133          // IN_CH + STATE_DIM
#define KPAD 160            // 5 k-steps of 32
#define NKSTEP 5
#define ASTRIDE 168         // LDS row stride (bf16 elems): 336B, 16B-aligned, bank-skewed

typedef short s16x8 __attribute__((ext_vector_type(8)));   // 8 bf16 in 4 VGPRs
typedef float f32x4 __attribute__((ext_vector_type(4)));

static __device__ __forceinline__ unsigned short f2bf(float f) {
    __hip_bfloat16 h = __float2bfloat16(f);   // RNE
    return *reinterpret_cast<unsigned short*>(&h);
}

// ---------------------------------------------------------------------------
// Repack W_neg[0:133] and W_root (both [*,128] fp32) into MFMA B-fragment
// order, bf16, K zero-padded to 160.
// Element (kk, nt, lane, j) = W[kk*32 + (lane>>4)*8 + j][nt*16 + (lane&15)]
// Grid: 2 mats x 5 kk x 8 nt = 80 blocks of 64.
// ---------------------------------------------------------------------------
__global__ __launch_bounds__(64) void repack_w(
    const float* __restrict__ Wneg, const float* __restrict__ Wroot,
    unsigned short* __restrict__ Pneg, unsigned short* __restrict__ Proot)
{
    int b = blockIdx.x;
    int mat = b / 40, r = b % 40;
    int kk = r / 8, nt = r % 8;
    int lane = threadIdx.x;
    const float* W = mat ? Wroot : Wneg;
    unsigned short* P = mat ? Proot : Pneg;
    int n = nt * 16 + (lane & 15);
    int kb = kk * 32 + (lane >> 4) * 8;
    unsigned short v[8];
#pragma unroll
    for (int j = 0; j < 8; ++j) {
        int k = kb + j;
        v[j] = (k < XS_DIM) ? f2bf(W[k * 128 + n]) : (unsigned short)0;
    }
    *(s16x8*)(P + ((size_t)(kk * 8 + nt) * 64 + lane) * 8) = *(s16x8*)v;
}

// ---------------------------------------------------------------------------
// MFMA node GEMM: 64 nodes/block, 4 waves; wave w owns rows w*16..w*16+15,
// all 128 cols (8 n-tiles), both matrices.
//   Yb[n]  = bf16( xs[n] @ Wneg[0:133] + b_neg )
//   out[n] = elu ( xs[n] @ Wroot       + b_root )
// ---------------------------------------------------------------------------
__global__ __launch_bounds__(256) void node_gemm_mfma(
    const float* __restrict__ x, const float* __restrict__ gs,
    const unsigned short* __restrict__ Pneg, const unsigned short* __restrict__ Proot,
    const float* __restrict__ bneg, const float* __restrict__ broot,
    __hip_bfloat16* __restrict__ Yb, float* __restrict__ out)
{
    __shared__ unsigned short Alds[64 * ASTRIDE];
    const int tid  = threadIdx.x;
    const int lane = tid & 63;
    const int wv   = tid >> 6;
    const int n0   = blockIdx.x * 64;

    // stage x -> LDS bf16 (A-layout is plain row-major [row][k], stride ASTRIDE)
#pragma unroll
    for (int i = 0; i < 16; ++i) {
        int row = i * 4 + wv;
        int nn  = min(n0 + row, N_NODES - 1);
        const float2 v = *(const float2*)(x + (size_t)nn * IN_CH + lane * 2);
        Alds[row * ASTRIDE + lane * 2]     = f2bf(v.x);
        Alds[row * ASTRIDE + lane * 2 + 1] = f2bf(v.y);
    }
    // global_state (k=128..132) + zero pad (k=133..159): one thread per row
    if (tid < 64) {
        int nn = min(n0 + tid, N_NODES - 1);
#pragma unroll
        for (int j = 0; j < STATE_DIM; ++j)
            Alds[tid * ASTRIDE + IN_CH + j] = f2bf(gs[(size_t)nn * STATE_DIM + j]);
#pragma unroll
        for (int k = XS_DIM; k < KPAD; ++k)
            Alds[tid * ASTRIDE + k] = 0;
    }
    __syncthreads();

    f32x4 accN[8], accR[8];
    const f32x4 zero = {0.f, 0.f, 0.f, 0.f};
#pragma unroll
    for (int nt = 0; nt < 8; ++nt) { accN[nt] = zero; accR[nt] = zero; }

    const int m = lane & 15, quad = lane >> 4;
    const unsigned short* arow = Alds + (wv * 16 + m) * ASTRIDE + quad * 8;

    for (int kk = 0; kk < NKSTEP; ++kk) {
        s16x8 a = *(const s16x8*)(arow + kk * 32);                  // ds_read_b128
        const unsigned short* bp = Pneg  + ((size_t)kk * 8 * 64 + lane) * 8;
        const unsigned short* rp = Proot + ((size_t)kk * 8 * 64 + lane) * 8;
#pragma unroll
        for (int nt = 0; nt < 8; ++nt) {
            s16x8 bn = *(const s16x8*)(bp + nt * 512);              // L1/L2-hot
            accN[nt] = __builtin_amdgcn_mfma_f32_16x16x32_bf16(a, bn, accN[nt], 0, 0, 0);
            s16x8 br = *(const s16x8*)(rp + nt * 512);
            accR[nt] = __builtin_amdgcn_mfma_f32_16x16x32_bf16(a, br, accR[nt], 0, 0, 0);
        }
    }

    // epilogue: C/D layout col=lane&15, row=quad*4+reg
#pragma unroll
    for (int nt = 0; nt < 8; ++nt) {
        int col = nt * 16 + m;
        float bn = bneg[col], br = broot[col];
        int rbase = n0 + wv * 16 + quad * 4;
#pragma unroll
        for (int r = 0; r < 4; ++r) {
            int node = rbase + r;
            if (node < N_NODES) {
                Yb[(size_t)node * 128 + col] = __float2bfloat16(accN[nt][r] + bn);
                float v = accR[nt][r] + br;
                out[(size_t)node * 128 + col] = (v > 0.f) ? v : (__expf(v) - 1.f);
            }
        }
    }
}

// ---------------------------------------------------------------------------
// CSR build: memsetAsync counts -> histogram -> single-block scan -> scatter
// ---------------------------------------------------------------------------
__global__ __launch_bounds__(256) void histogram(const int* __restrict__ idx,
                                                 int* __restrict__ cnt) {
    int e = blockIdx.x * 256 + threadIdx.x;
    if (e < N_EDGES) atomicAdd(&cnt[idx[e]], 1);
}

__global__ __launch_bounds__(1024) void scan_counts(const int* __restrict__ cnt,
                                                    int* __restrict__ off,
                                                    int* __restrict__ cursor) {
    __shared__ int wsum[16];
    const int tid  = threadIdx.x;
    const int lane = tid & 63;
    const int wid  = tid >> 6;
    int carry = 0;
    for (int c0 = 0; c0 < N_NODES; c0 += 16384) {
        int i0 = c0 + tid * 16;
        int v[16], s = 0;
#pragma unroll
        for (int j = 0; j < 16; ++j) {
            v[j] = (i0 + j < N_NODES) ? cnt[i0 + j] : 0;
            s += v[j];
        }
        int x = s;
#pragma unroll
        for (int d = 1; d < 64; d <<= 1) {
            int t = __shfl_up(x, d);
            if (lane >= d) x += t;
        }
        if (lane == 63) wsum[wid] = x;
        __syncthreads();
        if (wid == 0 && lane < 16) {
            int w = wsum[lane];
#pragma unroll
            for (int d = 1; d < 16; d <<= 1) {
                int t = __shfl_up(w, d);
                if (lane >= d) w += t;
            }
            wsum[lane] = w;
        }
        __syncthreads();
        int wprefix = (wid > 0) ? wsum[wid - 1] : 0;
        int total   = wsum[15];
        int excl = carry + wprefix + (x - s);
#pragma unroll
        for (int j = 0; j < 16; ++j) {
            if (i0 + j < N_NODES) { off[i0 + j] = excl; cursor[i0 + j] = excl; }
            excl += v[j];
        }
        carry += total;
        __syncthreads();
    }
}

__global__ __launch_bounds__(256) void scatter_edges(const int* __restrict__ idx,
                                                     int* __restrict__ cursor,
                                                     int* __restrict__ eids) {
    int e = blockIdx.x * 256 + threadIdx.x;
    if (e < N_EDGES) {
        int pos = atomicAdd(&cursor[idx[e]], 1);
        eids[pos] = e;
    }
}

// ---------------------------------------------------------------------------
// Aggregate: one wave per dst node; Y bf16 expanded exactly via bits<<16;
// fast __expf for the ELU.
// ---------------------------------------------------------------------------
__global__ __launch_bounds__(256) void aggregate(
    const int* __restrict__ idx,
    const float* __restrict__ ea,
    const float* __restrict__ Wneg,  // bottom 6 rows at 133*128
    const __hip_bfloat16* __restrict__ Yb,
    const int* __restrict__ off, const int* __restrict__ cnt,
    const int* __restrict__ eids,
    float* __restrict__ out)
{
    const int lane = threadIdx.x & 63;
    const int n    = blockIdx.x * 4 + (threadIdx.x >> 6);
    if (n >= N_NODES) return;

    const float2* wb2 = (const float2*)(Wneg + 133 * 128);
    float2 wb[EDGE_DIM];
#pragma unroll
    for (int j = 0; j < EDGE_DIM; ++j) wb[j] = wb2[j * 64 + lane];

    const int start = off[n];
    const int deg   = cnt[n];
    float accx = 0.f, accy = 0.f;

    for (int base = 0; base < deg; base += 64) {
        const int m = min(64, deg - base);
        int src = 0;
        float ea6[EDGE_DIM];
#pragma unroll
        for (int j = 0; j < EDGE_DIM; ++j) ea6[j] = 0.f;
        if (lane < m) {
            int eid = eids[start + base + lane];
            src = idx[N_EDGES + eid];
            const float* er = ea + (size_t)eid * EDGE_DIM;
#pragma unroll
            for (int j = 0; j < EDGE_DIM; ++j) ea6[j] = er[j];
        }
#pragma unroll 4
        for (int e = 0; e < m; ++e) {
            int s = __shfl(src, e);
            ushort2 u = ((const ushort2*)(Yb + (size_t)s * 128))[lane];
            float tx = __uint_as_float((unsigned)u.x << 16);
            float ty = __uint_as_float((unsigned)u.y << 16);
#pragma unroll
            for (int j = 0; j < EDGE_DIM; ++j) {
                float a = __shfl(ea6[j], e);
                tx = fmaf(a, wb[j].x, tx);
                ty = fmaf(a, wb[j].y, ty);
            }
            tx = (tx > 0.f) ? tx : (__expf(tx) - 1.f);
            ty = (ty > 0.f) ? ty : (__expf(ty) - 1.f);
            accx += tx;
            accy += ty;
        }
    }

    float2* orow = (float2*)(out + (size_t)n * 128);
    float2 o = orow[lane];
    o.x += accx;
    o.y += accy;
    orow[lane] = o;
}

extern "C" void kernel_launch(void* const* d_in, const int* in_sizes, int n_in,
                              void* d_out, int out_size, void* d_ws, size_t ws_size,
                              hipStream_t stream) {
    const float* x     = (const float*)d_in[0];
    const int*   idx   = (const int*)  d_in[1];
    const float* ea    = (const float*)d_in[2];
    const float* gs    = (const float*)d_in[3];
    const float* Wneg  = (const float*)d_in[4];
    const float* bneg  = (const float*)d_in[5];
    const float* Wroot = (const float*)d_in[6];
    const float* broot = (const float*)d_in[7];
    float* out = (float*)d_out;

    // ws layout:
    //   Yb    : N*128 bf16 (25.6 MB)
    //   cnt/off/cur : N int each
    //   eids  : E int (6.4 MB)
    //   Pneg/Proot : 20480 ushort each (packed weights)
    char* w = (char*)d_ws;
    __hip_bfloat16* Yb = (__hip_bfloat16*)w;      w += (size_t)N_NODES * 128 * 2;
    int* cnt  = (int*)w;                          w += (size_t)N_NODES * 4;
    int* off  = (int*)w;                          w += (size_t)N_NODES * 4;
    int* cur  = (int*)w;                          w += (size_t)N_NODES * 4;
    int* eids = (int*)w;                          w += (size_t)N_EDGES * 4;
    unsigned short* Pneg  = (unsigned short*)w;   w += (size_t)NKSTEP * 8 * 64 * 8 * 2;
    unsigned short* Proot = (unsigned short*)w;

    const int nb_edges = (N_EDGES + 255) / 256;

    repack_w<<<80, 64, 0, stream>>>(Wneg, Wroot, Pneg, Proot);
    node_gemm_mfma<<<(N_NODES + 63) / 64, 256, 0, stream>>>(
        x, gs, Pneg, Proot, bneg, broot, Yb, out);
    hipMemsetAsync(cnt, 0, (size_t)N_NODES * 4, stream);
    histogram<<<nb_edges, 256, 0, stream>>>(idx, cnt);
    scan_counts<<<1, 1024, 0, stream>>>(cnt, off, cur);
    scatter_edges<<<nb_edges, 256, 0, stream>>>(idx, cur, eids);
    aggregate<<<(N_NODES + 3) / 4, 256, 0, stream>>>(idx, ea, Wneg, Yb, off, cnt, eids, out);
}

// Round 5
// 482.745 us; speedup vs baseline: 1.5115x; 1.3752x over previous
//
#include <hip/hip_runtime.h>
#include <hip/hip_bf16.h>
#include <math.h>

#define N_NODES 100000
#define N_EDGES 1600000
#define IN_CH 128
#define OUT_CH 128
#define EDGE_DIM 6
#define STATE_DIM 5
#define XS_DIM 133          // IN_CH + STATE_DIM
#define KPAD 160            // 5 k-steps of 32
#define NKSTEP 5
#define ASTRIDE 168         // LDS row stride (bf16 elems)
#define NBLK 391            // ceil(N_NODES/256)

typedef short s16x8 __attribute__((ext_vector_type(8)));
typedef float f32x4 __attribute__((ext_vector_type(4)));

static __device__ __forceinline__ unsigned short f2bf(float f) {
    __hip_bfloat16 h = __float2bfloat16(f);   // RNE
    return *reinterpret_cast<unsigned short*>(&h);
}
static __device__ __forceinline__ float bflo(unsigned u) {   // low bf16 -> f32
    return __uint_as_float(u << 16);
}
static __device__ __forceinline__ float bfhi(unsigned u) {   // high bf16 -> f32
    return __uint_as_float(u & 0xffff0000u);
}

// ---------------------------------------------------------------------------
// Repack W_neg[0:133], W_root into MFMA B-fragment order, bf16, K padded 160.
// ---------------------------------------------------------------------------
__global__ __launch_bounds__(64) void repack_w(
    const float* __restrict__ Wneg, const float* __restrict__ Wroot,
    unsigned short* __restrict__ Pneg, unsigned short* __restrict__ Proot)
{
    int b = blockIdx.x;
    int mat = b / 40, r = b % 40;
    int kk = r / 8, nt = r % 8;
    int lane = threadIdx.x;
    const float* W = mat ? Wroot : Wneg;
    unsigned short* P = mat ? Proot : Pneg;
    int n = nt * 16 + (lane & 15);
    int kb = kk * 32 + (lane >> 4) * 8;
    unsigned short v[8];
#pragma unroll
    for (int j = 0; j < 8; ++j) {
        int k = kb + j;
        v[j] = (k < XS_DIM) ? f2bf(W[k * 128 + n]) : (unsigned short)0;
    }
    *(s16x8*)(P + ((size_t)(kk * 8 + nt) * 64 + lane) * 8) = *(s16x8*)v;
}

// ---------------------------------------------------------------------------
// MFMA node GEMM: 64 nodes/block, 4 waves.
// ---------------------------------------------------------------------------
__global__ __launch_bounds__(256) void node_gemm_mfma(
    const float* __restrict__ x, const float* __restrict__ gs,
    const unsigned short* __restrict__ Pneg, const unsigned short* __restrict__ Proot,
    const float* __restrict__ bneg, const float* __restrict__ broot,
    __hip_bfloat16* __restrict__ Yb, float* __restrict__ out)
{
    __shared__ unsigned short Alds[64 * ASTRIDE];
    const int tid  = threadIdx.x;
    const int lane = tid & 63;
    const int wv   = tid >> 6;
    const int n0   = blockIdx.x * 64;

#pragma unroll
    for (int i = 0; i < 16; ++i) {
        int row = i * 4 + wv;
        int nn  = min(n0 + row, N_NODES - 1);
        const float2 v = *(const float2*)(x + (size_t)nn * IN_CH + lane * 2);
        Alds[row * ASTRIDE + lane * 2]     = f2bf(v.x);
        Alds[row * ASTRIDE + lane * 2 + 1] = f2bf(v.y);
    }
    if (tid < 64) {
        int nn = min(n0 + tid, N_NODES - 1);
#pragma unroll
        for (int j = 0; j < STATE_DIM; ++j)
            Alds[tid * ASTRIDE + IN_CH + j] = f2bf(gs[(size_t)nn * STATE_DIM + j]);
#pragma unroll
        for (int k = XS_DIM; k < KPAD; ++k)
            Alds[tid * ASTRIDE + k] = 0;
    }
    __syncthreads();

    f32x4 accN[8], accR[8];
    const f32x4 zero = {0.f, 0.f, 0.f, 0.f};
#pragma unroll
    for (int nt = 0; nt < 8; ++nt) { accN[nt] = zero; accR[nt] = zero; }

    const int m = lane & 15, quad = lane >> 4;
    const unsigned short* arow = Alds + (wv * 16 + m) * ASTRIDE + quad * 8;

    for (int kk = 0; kk < NKSTEP; ++kk) {
        s16x8 a = *(const s16x8*)(arow + kk * 32);
        const unsigned short* bp = Pneg  + ((size_t)kk * 8 * 64 + lane) * 8;
        const unsigned short* rp = Proot + ((size_t)kk * 8 * 64 + lane) * 8;
#pragma unroll
        for (int nt = 0; nt < 8; ++nt) {
            s16x8 bn = *(const s16x8*)(bp + nt * 512);
            accN[nt] = __builtin_amdgcn_mfma_f32_16x16x32_bf16(a, bn, accN[nt], 0, 0, 0);
            s16x8 br = *(const s16x8*)(rp + nt * 512);
            accR[nt] = __builtin_amdgcn_mfma_f32_16x16x32_bf16(a, br, accR[nt], 0, 0, 0);
        }
    }

#pragma unroll
    for (int nt = 0; nt < 8; ++nt) {
        int col = nt * 16 + m;
        float bn = bneg[col], br = broot[col];
        int rbase = n0 + wv * 16 + quad * 4;
#pragma unroll
        for (int r = 0; r < 4; ++r) {
            int node = rbase + r;
            if (node < N_NODES) {
                Yb[(size_t)node * 128 + col] = __float2bfloat16(accN[nt][r] + bn);
                float v = accR[nt][r] + br;
                out[(size_t)node * 128 + col] = (v > 0.f) ? v : (__expf(v) - 1.f);
            }
        }
    }
}

// ---------------------------------------------------------------------------
// CSR build: memset -> histogram -> 3-pass scan -> payload scatter
// ---------------------------------------------------------------------------
__global__ __launch_bounds__(256) void histogram(const int* __restrict__ idx,
                                                 int* __restrict__ cnt) {
    int e = blockIdx.x * 256 + threadIdx.x;
    if (e < N_EDGES) atomicAdd(&cnt[idx[e]], 1);
}

__global__ __launch_bounds__(256) void scan_block_sums(const int* __restrict__ cnt,
                                                       int* __restrict__ bsum) {
    __shared__ int ws[4];
    int tid = threadIdx.x, lane = tid & 63, wid = tid >> 6;
    int i = blockIdx.x * 256 + tid;
    int v = (i < N_NODES) ? cnt[i] : 0;
#pragma unroll
    for (int d = 32; d > 0; d >>= 1) v += __shfl_down(v, d);
    if (lane == 0) ws[wid] = v;
    __syncthreads();
    if (tid == 0) bsum[blockIdx.x] = ws[0] + ws[1] + ws[2] + ws[3];
}

__global__ __launch_bounds__(512) void scan_bsums(int* __restrict__ bsum) {
    __shared__ int s[512];
    int tid = threadIdx.x;
    int v = (tid < NBLK) ? bsum[tid] : 0;
    s[tid] = v;
    __syncthreads();
    for (int d = 1; d < 512; d <<= 1) {
        int t = (tid >= d) ? s[tid - d] : 0;
        __syncthreads();
        s[tid] += t;
        __syncthreads();
    }
    if (tid < NBLK) bsum[tid] = s[tid] - v;   // exclusive
}

__global__ __launch_bounds__(256) void scan_final(const int* __restrict__ cnt,
                                                  const int* __restrict__ bsum,
                                                  int* __restrict__ off,
                                                  int* __restrict__ cursor) {
    __shared__ int wsum[4];
    int tid = threadIdx.x, lane = tid & 63, wid = tid >> 6;
    int i = blockIdx.x * 256 + tid;
    int v = (i < N_NODES) ? cnt[i] : 0;
    int x = v;
#pragma unroll
    for (int d = 1; d < 64; d <<= 1) {
        int t = __shfl_up(x, d);
        if (lane >= d) x += t;
    }
    if (lane == 63) wsum[wid] = x;
    __syncthreads();
    int wpre = 0;
#pragma unroll
    for (int j = 0; j < 4; ++j) wpre += (j < wid) ? wsum[j] : 0;
    int excl = bsum[blockIdx.x] + wpre + x - v;
    if (i < N_NODES) { off[i] = excl; cursor[i] = excl; }
}

// payload slot: {src:int, ea packed as 3x(bf16,bf16)} = 16B
__global__ __launch_bounds__(256) void scatter_edges(const int* __restrict__ idx,
                                                     const float* __restrict__ ea,
                                                     int* __restrict__ cursor,
                                                     uint4* __restrict__ pay) {
    int e = blockIdx.x * 256 + threadIdx.x;
    if (e < N_EDGES) {
        int dst = idx[e];
        int src = idx[N_EDGES + e];
        const float* er = ea + (size_t)e * EDGE_DIM;
        unsigned p0 = (unsigned)f2bf(er[0]) | ((unsigned)f2bf(er[1]) << 16);
        unsigned p1 = (unsigned)f2bf(er[2]) | ((unsigned)f2bf(er[3]) << 16);
        unsigned p2 = (unsigned)f2bf(er[4]) | ((unsigned)f2bf(er[5]) << 16);
        int pos = atomicAdd(&cursor[dst], 1);
        uint4 pl = { (unsigned)src, p0, p1, p2 };
        pay[pos] = pl;
    }
}

// ---------------------------------------------------------------------------
// Aggregate: one wave per dst node. Payload coalesced; readlane broadcasts
// (no DS latency); 8 Y-row loads in flight per batch.
// ---------------------------------------------------------------------------
__global__ __launch_bounds__(256) void aggregate(
    const uint4* __restrict__ pay,
    const float* __restrict__ Wneg,  // bottom 6 rows at 133*128
    const __hip_bfloat16* __restrict__ Yb,
    const int* __restrict__ off, const int* __restrict__ cnt,
    float* __restrict__ out)
{
    const int lane = threadIdx.x & 63;
    const int n    = blockIdx.x * 4 + (threadIdx.x >> 6);
    if (n >= N_NODES) return;

    const float2* wb2 = (const float2*)(Wneg + 133 * 128);
    float2 wb[EDGE_DIM];
#pragma unroll
    for (int j = 0; j < EDGE_DIM; ++j) wb[j] = wb2[j * 64 + lane];

    const unsigned* Yu = (const unsigned*)Yb;   // 64 uints per row
    const int start = off[n];
    const int deg   = cnt[n];
    float accx = 0.f, accy = 0.f;

    for (int base = 0; base < deg; base += 64) {
        const int m = min(64, deg - base);
        uint4 pl = { 0u, 0u, 0u, 0u };
        if (lane < m) pl = pay[start + base + lane];
        int src_l = (int)pl.x;
        int ea0 = (int)pl.y, ea1 = (int)pl.z, ea2 = (int)pl.w;

        for (int e0 = 0; e0 < m; e0 += 8) {
            const int mm = min(8, m - e0);
            unsigned yv[8];
#pragma unroll
            for (int c = 0; c < 8; ++c) {
                if (c < mm) {
                    int s = __builtin_amdgcn_readlane(src_l, e0 + c);
                    yv[c] = Yu[(size_t)s * 64 + lane];
                }
            }
#pragma unroll
            for (int c = 0; c < 8; ++c) {
                if (c < mm) {
                    unsigned u = yv[c];
                    float tx = bflo(u), ty = bfhi(u);
                    unsigned a0 = (unsigned)__builtin_amdgcn_readlane(ea0, e0 + c);
                    unsigned a1 = (unsigned)__builtin_amdgcn_readlane(ea1, e0 + c);
                    unsigned a2 = (unsigned)__builtin_amdgcn_readlane(ea2, e0 + c);
                    float f0 = bflo(a0), f1 = bfhi(a0);
                    float f2 = bflo(a1), f3 = bfhi(a1);
                    float f4 = bflo(a2), f5 = bfhi(a2);
                    tx = fmaf(f0, wb[0].x, tx); ty = fmaf(f0, wb[0].y, ty);
                    tx = fmaf(f1, wb[1].x, tx); ty = fmaf(f1, wb[1].y, ty);
                    tx = fmaf(f2, wb[2].x, tx); ty = fmaf(f2, wb[2].y, ty);
                    tx = fmaf(f3, wb[3].x, tx); ty = fmaf(f3, wb[3].y, ty);
                    tx = fmaf(f4, wb[4].x, tx); ty = fmaf(f4, wb[4].y, ty);
                    tx = fmaf(f5, wb[5].x, tx); ty = fmaf(f5, wb[5].y, ty);
                    tx = (tx > 0.f) ? tx : (__expf(tx) - 1.f);
                    ty = (ty > 0.f) ? ty : (__expf(ty) - 1.f);
                    accx += tx;
                    accy += ty;
                }
            }
        }
    }

    float2* orow = (float2*)(out + (size_t)n * 128);
    float2 o = orow[lane];
    o.x += accx;
    o.y += accy;
    orow[lane] = o;
}

extern "C" void kernel_launch(void* const* d_in, const int* in_sizes, int n_in,
                              void* d_out, int out_size, void* d_ws, size_t ws_size,
                              hipStream_t stream) {
    const float* x     = (const float*)d_in[0];
    const int*   idx   = (const int*)  d_in[1];
    const float* ea    = (const float*)d_in[2];
    const float* gs    = (const float*)d_in[3];
    const float* Wneg  = (const float*)d_in[4];
    const float* bneg  = (const float*)d_in[5];
    const float* Wroot = (const float*)d_in[6];
    const float* broot = (const float*)d_in[7];
    float* out = (float*)d_out;

    // ws layout (16B-aligned sections):
    //   Yb      : N*128 bf16           25.6 MB
    //   cnt/off/cur : N int each        1.2 MB
    //   bsum    : NBLK int (pad 2KB)
    //   pay     : E * 16B              25.6 MB
    //   Pneg/Proot : 40 KB each
    char* w = (char*)d_ws;
    __hip_bfloat16* Yb = (__hip_bfloat16*)w;      w += (size_t)N_NODES * 128 * 2;
    int* cnt  = (int*)w;                          w += (size_t)N_NODES * 4;
    int* off  = (int*)w;                          w += (size_t)N_NODES * 4;
    int* cur  = (int*)w;                          w += (size_t)N_NODES * 4;
    int* bsum = (int*)w;                          w += 2048;
    uint4* pay = (uint4*)w;                       w += (size_t)N_EDGES * 16;
    unsigned short* Pneg  = (unsigned short*)w;   w += (size_t)NKSTEP * 8 * 64 * 8 * 2;
    unsigned short* Proot = (unsigned short*)w;

    const int nb_edges = (N_EDGES + 255) / 256;

    repack_w<<<80, 64, 0, stream>>>(Wneg, Wroot, Pneg, Proot);
    node_gemm_mfma<<<(N_NODES + 63) / 64, 256, 0, stream>>>(
        x, gs, Pneg, Proot, bneg, broot, Yb, out);
    hipMemsetAsync(cnt, 0, (size_t)N_NODES * 4, stream);
    histogram<<<nb_edges, 256, 0, stream>>>(idx, cnt);
    scan_block_sums<<<NBLK, 256, 0, stream>>>(cnt, bsum);
    scan_bsums<<<1, 512, 0, stream>>>(bsum);
    scan_final<<<NBLK, 256, 0, stream>>>(cnt, bsum, off, cur);
    scatter_edges<<<nb_edges, 256, 0, stream>>>(idx, ea, cur, pay);
    aggregate<<<(N_NODES + 3) / 4, 256, 0, stream>>>(pay, Wneg, Yb, off, cnt, out);
}